// Round 2
// baseline (243.100 us; speedup 1.0000x reference)
//
#include <hip/hip_runtime.h>

// IncrementalRobertaSelfAttentionCross: B=4, Sq=1024, Skv=2048 (enc||dec), D=1024, H=16, HD=64
// Pipeline: Wt cast/transpose -> QKV GEMM (fp16 MFMA, fp32 accum) -> V transpose -> flash attn.

typedef _Float16 f16;
typedef __attribute__((ext_vector_type(8))) _Float16 half8;
typedef __attribute__((ext_vector_type(4))) float floatx4;

// ---------------------------------------------------------------- W transpose
// W [1024 k][1024 n] f32  ->  Wt [1024 n][1024 k] f16
__global__ void wt_kernel(const float* __restrict__ W, f16* __restrict__ Wt) {
    __shared__ float tile[32][33];
    int k0 = blockIdx.y * 32, n0 = blockIdx.x * 32;
    int tx = threadIdx.x, ty = threadIdx.y;   // block (32,8)
    #pragma unroll
    for (int i = 0; i < 32; i += 8)
        tile[ty + i][tx] = W[(k0 + ty + i) * 1024 + n0 + tx];
    __syncthreads();
    #pragma unroll
    for (int i = 0; i < 32; i += 8)
        Wt[(n0 + ty + i) * 1024 + k0 + tx] = (f16)tile[tx][ty + i];
}

// ---------------------------------------------------------------- V transpose
// V [bh][2048 s][64 d] f16 -> Vt [bh][64 d][2048 s] f16
__global__ void vt_kernel(const f16* __restrict__ V, f16* __restrict__ Vt) {
    __shared__ f16 tile[32][33];
    int bh = blockIdx.z;
    int s0 = blockIdx.y * 32, d0 = blockIdx.x * 32;
    int tx = threadIdx.x, ty = threadIdx.y;   // block (32,8)
    const f16* Vp = V + (size_t)bh * 2048 * 64;
    f16* Vtp = Vt + (size_t)bh * 64 * 2048;
    #pragma unroll
    for (int i = 0; i < 32; i += 8)
        tile[ty + i][tx] = Vp[(s0 + ty + i) * 64 + d0 + tx];
    __syncthreads();
    #pragma unroll
    for (int i = 0; i < 32; i += 8)
        Vtp[(d0 + ty + i) * 2048 + s0 + tx] = tile[tx][ty + i];
}

// ---------------------------------------------------------------- QKV GEMM
// C = A(f32)[M x 1024] * W[1024 x 1024] + bias, emitted as f16 in [B,H,S,64] layout.
// mode 0: Q  (M=4096, rows from hid)
// mode 1: K  (M=8192, rows from concat(enc, hid) per batch)
// mode 2: V  (same rows as K)
__launch_bounds__(256)
__global__ void qkv_gemm(const float* __restrict__ hid, const float* __restrict__ enc,
                         const f16* __restrict__ Wt, const float* __restrict__ bias,
                         f16* __restrict__ out, int mode) {
    __shared__ f16 At[128 * 40];   // 128 rows x 32 k, stride 40 (pad breaks pow2)
    __shared__ f16 Bt[128 * 40];   // 128 n-rows x 32 k

    int tid = threadIdx.x;
    int m0 = blockIdx.x * 128, n0 = blockIdx.y * 128;
    int wid = tid >> 6, lane = tid & 63;
    int wm = (wid >> 1) * 64, wn = (wid & 1) * 64;
    int lr = lane & 15, lg = lane >> 4;

    floatx4 acc[4][4];
    #pragma unroll
    for (int i = 0; i < 4; i++)
        #pragma unroll
        for (int j = 0; j < 4; j++) acc[i][j] = (floatx4)(0.f);

    // A staging: thread loads 4 rows x 1 float4
    int tk = tid & 7, tr = tid >> 3;
    const float* arow[4];
    #pragma unroll
    for (int p = 0; p < 4; p++) {
        int m = m0 + tr + p * 32;
        if (mode == 0) {
            int b = m >> 10, s = m & 1023;
            arow[p] = hid + (size_t)(b * 1024 + s) * 1024;
        } else {
            int b = m >> 11, s = m & 2047;
            arow[p] = (s < 1024) ? enc + (size_t)(b * 1024 + s) * 1024
                                 : hid + (size_t)(b * 1024 + (s - 1024)) * 1024;
        }
    }
    // B staging: thread loads 2 rows x 8 halves
    int tk2 = (tid & 3) * 8, tr2 = tid >> 2;
    const f16* brow0 = Wt + (size_t)(n0 + tr2) * 1024 + tk2;
    const f16* brow1 = Wt + (size_t)(n0 + tr2 + 64) * 1024 + tk2;

    for (int k0 = 0; k0 < 1024; k0 += 32) {
        #pragma unroll
        for (int p = 0; p < 4; p++) {
            float4 v = *(const float4*)(arow[p] + k0 + tk * 4);
            f16* dst = &At[(tr + p * 32) * 40 + tk * 4];
            dst[0] = (f16)v.x; dst[1] = (f16)v.y; dst[2] = (f16)v.z; dst[3] = (f16)v.w;
        }
        *(half8*)&Bt[tr2 * 40 + tk2]        = *(const half8*)(brow0 + k0);
        *(half8*)&Bt[(tr2 + 64) * 40 + tk2] = *(const half8*)(brow1 + k0);
        __syncthreads();

        half8 a[4], bf[4];
        #pragma unroll
        for (int i = 0; i < 4; i++)
            a[i] = *(const half8*)&At[(wm + i * 16 + lr) * 40 + lg * 8];
        #pragma unroll
        for (int j = 0; j < 4; j++)
            bf[j] = *(const half8*)&Bt[(wn + j * 16 + lr) * 40 + lg * 8];
        #pragma unroll
        for (int i = 0; i < 4; i++)
            #pragma unroll
            for (int j = 0; j < 4; j++)
                acc[i][j] = __builtin_amdgcn_mfma_f32_16x16x32_f16(a[i], bf[j], acc[i][j], 0, 0, 0);
        __syncthreads();
    }

    int Sout = (mode == 0) ? 1024 : 2048;
    #pragma unroll
    for (int i = 0; i < 4; i++) {
        int mbase = m0 + wm + i * 16 + lg * 4;
        #pragma unroll
        for (int j = 0; j < 4; j++) {
            int n = n0 + wn + j * 16 + lr;
            int h = n >> 6, d = n & 63;
            float bv = bias[n];
            #pragma unroll
            for (int r = 0; r < 4; r++) {
                int m = mbase + r;
                int b = (mode == 0) ? (m >> 10) : (m >> 11);
                int s = (mode == 0) ? (m & 1023) : (m & 2047);
                out[((size_t)(b * 16 + h) * Sout + s) * 64 + d] = (f16)(acc[i][j][r] + bv);
            }
        }
    }
}

// ---------------------------------------------------------------- flash attention
// Q [bh][1024][64], K [bh][2048][64], Vt [bh][64][2048] (all f16), mask [B][2048] f32
// out [B][1024][1024] f32. Block: 256 thr = 4 waves, each wave owns 16 q-rows; KV tile 64.
__launch_bounds__(256)
__global__ void attn_kernel(const f16* __restrict__ Q, const f16* __restrict__ K,
                            const f16* __restrict__ Vt, const float* __restrict__ mask,
                            float* __restrict__ out) {
    __shared__ f16 Kt[64 * 72];       // [kv][d], stride 72
    __shared__ f16 Vtt[64 * 72];      // [d][kv], stride 72
    __shared__ f16 Pl[4][16 * 72];    // per-wave P [qrow][kv]

    int tid = threadIdx.x;
    int wid = tid >> 6, lane = tid & 63;
    int lr = lane & 15, lg = lane >> 4;
    int bh = blockIdx.y, b = bh >> 4, h = bh & 15;
    int q0 = blockIdx.x * 64 + wid * 16;

    // Q fragments (A-operand): lane holds Q[q0+lr][8*lg + j + 32*c]
    const f16* qrow = Q + ((size_t)bh * 1024 + q0 + lr) * 64;
    half8 qf[2];
    qf[0] = *(const half8*)(qrow + lg * 8);
    qf[1] = *(const half8*)(qrow + 32 + lg * 8);

    floatx4 o[4];
    #pragma unroll
    for (int j = 0; j < 4; j++) o[j] = (floatx4)(0.f);
    float mrow[4], lrow[4];
    #pragma unroll
    for (int i = 0; i < 4; i++) { mrow[i] = -1e30f; lrow[i] = 0.f; }

    const float* maskp = mask + b * 2048;
    int sr = tid >> 3, sc = (tid & 7) * 8;

    for (int kv0 = 0; kv0 < 2048; kv0 += 64) {
        #pragma unroll
        for (int p = 0; p < 2; p++) {
            int row = sr + p * 32;
            *(half8*)&Kt[row * 72 + sc]  = *(const half8*)(K  + ((size_t)bh * 2048 + kv0 + row) * 64 + sc);
            *(half8*)&Vtt[row * 72 + sc] = *(const half8*)(Vt + ((size_t)bh * 64 + row) * 2048 + kv0 + sc);
        }
        __syncthreads();

        // S = Q K^T  (row = q-offset, col = kv-offset within 16-tile t)
        floatx4 sf[4];
        #pragma unroll
        for (int t = 0; t < 4; t++) sf[t] = (floatx4)(0.f);
        #pragma unroll
        for (int t = 0; t < 4; t++)
            #pragma unroll
            for (int c = 0; c < 2; c++) {
                half8 kf = *(const half8*)&Kt[(t * 16 + lr) * 72 + c * 32 + lg * 8];
                sf[t] = __builtin_amdgcn_mfma_f32_16x16x32_f16(qf[c], kf, sf[t], 0, 0, 0);
            }

        float sv[4][4];
        #pragma unroll
        for (int t = 0; t < 4; t++) {
            float mk = maskp[kv0 + t * 16 + lr];
            #pragma unroll
            for (int i = 0; i < 4; i++) sv[t][i] = sf[t][i] * 0.125f + mk;
        }

        // online softmax (rows lg*4+i, reduce across the 16-lane column group)
        #pragma unroll
        for (int i = 0; i < 4; i++) {
            float mx = fmaxf(fmaxf(sv[0][i], sv[1][i]), fmaxf(sv[2][i], sv[3][i]));
            mx = fmaxf(mx, __shfl_xor(mx, 1));
            mx = fmaxf(mx, __shfl_xor(mx, 2));
            mx = fmaxf(mx, __shfl_xor(mx, 4));
            mx = fmaxf(mx, __shfl_xor(mx, 8));
            float nm = fmaxf(mrow[i], mx);
            float rs = 0.f;
            #pragma unroll
            for (int t = 0; t < 4; t++) {
                float p = __expf(sv[t][i] - nm);
                sv[t][i] = p;
                rs += p;
            }
            rs += __shfl_xor(rs, 1);
            rs += __shfl_xor(rs, 2);
            rs += __shfl_xor(rs, 4);
            rs += __shfl_xor(rs, 8);
            float alpha = __expf(mrow[i] - nm);
            lrow[i] = lrow[i] * alpha + rs;
            mrow[i] = nm;
            #pragma unroll
            for (int j = 0; j < 4; j++) o[j][i] *= alpha;
        }

        // P -> LDS (per-wave buffer), then PV
        f16* pl = Pl[wid];
        #pragma unroll
        for (int t = 0; t < 4; t++)
            #pragma unroll
            for (int i = 0; i < 4; i++)
                pl[(lg * 4 + i) * 72 + t * 16 + lr] = (f16)sv[t][i];

        #pragma unroll
        for (int c = 0; c < 2; c++) {
            half8 pf = *(const half8*)&pl[lr * 72 + c * 32 + lg * 8];
            #pragma unroll
            for (int j = 0; j < 4; j++) {
                half8 vf = *(const half8*)&Vtt[(j * 16 + lr) * 72 + c * 32 + lg * 8];
                o[j] = __builtin_amdgcn_mfma_f32_16x16x32_f16(pf, vf, o[j], 0, 0, 0);
            }
        }
        __syncthreads();
    }

    #pragma unroll
    for (int i = 0; i < 4; i++) {
        int q = q0 + lg * 4 + i;
        float inv = 1.f / lrow[i];
        #pragma unroll
        for (int j = 0; j < 4; j++) {
            int d = j * 16 + lr;
            out[((size_t)(b * 1024 + q)) * 1024 + h * 64 + d] = o[j][i] * inv;
        }
    }
}

// ---------------------------------------------------------------- launcher
extern "C" void kernel_launch(void* const* d_in, const int* in_sizes, int n_in,
                              void* d_out, int out_size, void* d_ws, size_t ws_size,
                              hipStream_t stream) {
    const float* hid  = (const float*)d_in[0];
    const float* enc  = (const float*)d_in[1];
    const float* mask = (const float*)d_in[2];
    const float* Wq   = (const float*)d_in[3];
    const float* bq   = (const float*)d_in[4];
    const float* Wk   = (const float*)d_in[5];
    const float* bk   = (const float*)d_in[6];
    const float* Wv   = (const float*)d_in[7];
    const float* bv   = (const float*)d_in[8];
    float* out = (float*)d_out;

    char* ws = (char*)d_ws;
    f16* Wtq = (f16*)(ws + (size_t)0);
    f16* Wtk = (f16*)(ws + ((size_t)2 << 20));
    f16* Wtv = (f16*)(ws + ((size_t)4 << 20));
    f16* Qw  = (f16*)(ws + ((size_t)6 << 20));
    f16* Kw  = (f16*)(ws + ((size_t)14 << 20));
    f16* Vw  = (f16*)(ws + ((size_t)30 << 20));
    f16* Vtw = (f16*)(ws + ((size_t)46 << 20));   // total 62 MiB

    dim3 tb(32, 8);
    wt_kernel<<<dim3(32, 32), tb, 0, stream>>>(Wq, Wtq);
    wt_kernel<<<dim3(32, 32), tb, 0, stream>>>(Wk, Wtk);
    wt_kernel<<<dim3(32, 32), tb, 0, stream>>>(Wv, Wtv);

    qkv_gemm<<<dim3(32, 8), 256, 0, stream>>>(hid, enc, Wtq, bq, Qw, 0);
    qkv_gemm<<<dim3(64, 8), 256, 0, stream>>>(hid, enc, Wtk, bk, Kw, 1);
    qkv_gemm<<<dim3(64, 8), 256, 0, stream>>>(hid, enc, Wtv, bv, Vw, 2);

    vt_kernel<<<dim3(2, 64, 64), tb, 0, stream>>>(Vw, Vtw);

    attn_kernel<<<dim3(16, 64), 256, 0, stream>>>(Qw, Kw, Vtw, mask, out);
}

// Round 4
// 197.430 us; speedup vs baseline: 1.2313x; 1.2313x over previous
//
#include <hip/hip_runtime.h>

// IncrementalRobertaSelfAttentionCross: B=4, Sq=1024, Skv=2048 (enc||dec), D=1024, H=16, HD=64
// Pipeline: Wt cast/transpose -> QKV GEMM (fp16 MFMA, fp32 accum) -> V transpose -> flash attn.
// Attn: 32x32x16 swapped-QK^T, in-register softmax, exp2 domain, defer-max.
// B-operand k-layout for 32x32x16 is probed at runtime (flat vs two-block) and both
// the Q-frag load and the P-pack adapt.

typedef _Float16 f16;
typedef __attribute__((ext_vector_type(4))) _Float16 half4;
typedef __attribute__((ext_vector_type(8))) _Float16 half8;
typedef __attribute__((ext_vector_type(4))) float floatx4;
typedef __attribute__((ext_vector_type(16))) float floatx16;
typedef __attribute__((ext_vector_type(4))) unsigned int uint4v;

// ---------------------------------------------------------------- W transpose
__global__ void wt_kernel(const float* __restrict__ W, f16* __restrict__ Wt) {
    __shared__ float tile[32][33];
    int k0 = blockIdx.y * 32, n0 = blockIdx.x * 32;
    int tx = threadIdx.x, ty = threadIdx.y;   // block (32,8)
    #pragma unroll
    for (int i = 0; i < 32; i += 8)
        tile[ty + i][tx] = W[(k0 + ty + i) * 1024 + n0 + tx];
    __syncthreads();
    #pragma unroll
    for (int i = 0; i < 32; i += 8)
        Wt[(n0 + ty + i) * 1024 + k0 + tx] = (f16)tile[tx][ty + i];
}

// ---------------------------------------------------------------- V transpose
__global__ void vt_kernel(const f16* __restrict__ V, f16* __restrict__ Vt) {
    __shared__ f16 tile[32][33];
    int bh = blockIdx.z;
    int s0 = blockIdx.y * 32, d0 = blockIdx.x * 32;
    int tx = threadIdx.x, ty = threadIdx.y;   // block (32,8)
    const f16* Vp = V + (size_t)bh * 2048 * 64;
    f16* Vtp = Vt + (size_t)bh * 64 * 2048;
    #pragma unroll
    for (int i = 0; i < 32; i += 8)
        tile[ty + i][tx] = Vp[(s0 + ty + i) * 64 + d0 + tx];
    __syncthreads();
    #pragma unroll
    for (int i = 0; i < 32; i += 8)
        Vtp[(d0 + ty + i) * 2048 + s0 + tx] = tile[tx][ty + i];
}

// ---------------------------------------------------------------- QKV GEMM
__launch_bounds__(256)
__global__ void qkv_gemm(const float* __restrict__ hid, const float* __restrict__ enc,
                         const f16* __restrict__ Wt, const float* __restrict__ bias,
                         f16* __restrict__ out, int mode) {
    __shared__ f16 At[128 * 40];
    __shared__ f16 Bt[128 * 40];

    int tid = threadIdx.x;
    int m0 = blockIdx.x * 128, n0 = blockIdx.y * 128;
    int wid = tid >> 6, lane = tid & 63;
    int wm = (wid >> 1) * 64, wn = (wid & 1) * 64;
    int lr = lane & 15, lg = lane >> 4;

    floatx4 acc[4][4];
    #pragma unroll
    for (int i = 0; i < 4; i++)
        #pragma unroll
        for (int j = 0; j < 4; j++) acc[i][j] = (floatx4)(0.f);

    int tk = tid & 7, tr = tid >> 3;
    const float* arow[4];
    #pragma unroll
    for (int p = 0; p < 4; p++) {
        int m = m0 + tr + p * 32;
        if (mode == 0) {
            int b = m >> 10, s = m & 1023;
            arow[p] = hid + (size_t)(b * 1024 + s) * 1024;
        } else {
            int b = m >> 11, s = m & 2047;
            arow[p] = (s < 1024) ? enc + (size_t)(b * 1024 + s) * 1024
                                 : hid + (size_t)(b * 1024 + (s - 1024)) * 1024;
        }
    }
    int tk2 = (tid & 3) * 8, tr2 = tid >> 2;
    const f16* brow0 = Wt + (size_t)(n0 + tr2) * 1024 + tk2;
    const f16* brow1 = Wt + (size_t)(n0 + tr2 + 64) * 1024 + tk2;

    for (int k0 = 0; k0 < 1024; k0 += 32) {
        #pragma unroll
        for (int p = 0; p < 4; p++) {
            float4 v = *(const float4*)(arow[p] + k0 + tk * 4);
            f16* dst = &At[(tr + p * 32) * 40 + tk * 4];
            dst[0] = (f16)v.x; dst[1] = (f16)v.y; dst[2] = (f16)v.z; dst[3] = (f16)v.w;
        }
        *(half8*)&Bt[tr2 * 40 + tk2]        = *(const half8*)(brow0 + k0);
        *(half8*)&Bt[(tr2 + 64) * 40 + tk2] = *(const half8*)(brow1 + k0);
        __syncthreads();

        half8 a[4], bf[4];
        #pragma unroll
        for (int i = 0; i < 4; i++)
            a[i] = *(const half8*)&At[(wm + i * 16 + lr) * 40 + lg * 8];
        #pragma unroll
        for (int j = 0; j < 4; j++)
            bf[j] = *(const half8*)&Bt[(wn + j * 16 + lr) * 40 + lg * 8];
        #pragma unroll
        for (int i = 0; i < 4; i++)
            #pragma unroll
            for (int j = 0; j < 4; j++)
                acc[i][j] = __builtin_amdgcn_mfma_f32_16x16x32_f16(a[i], bf[j], acc[i][j], 0, 0, 0);
        __syncthreads();
    }

    int Sout = (mode == 0) ? 1024 : 2048;
    #pragma unroll
    for (int i = 0; i < 4; i++) {
        int mbase = m0 + wm + i * 16 + lg * 4;
        #pragma unroll
        for (int j = 0; j < 4; j++) {
            int n = n0 + wn + j * 16 + lr;
            int h = n >> 6, d = n & 63;
            float bv = bias[n];
            #pragma unroll
            for (int r = 0; r < 4; r++) {
                int m = mbase + r;
                int b = (mode == 0) ? (m >> 10) : (m >> 11);
                int s = (mode == 0) ? (m & 1023) : (m & 2047);
                out[((size_t)(b * 16 + h) * Sout + s) * 64 + d] = (f16)(acc[i][j][r] + bv);
            }
        }
    }
}

// ---------------------------------------------------------------- flash attention
__device__ inline half8 pack_swap(float s0, float s1, float s2, float s3,
                                  float s4, float s5, float s6, float s7) {
    unsigned a0 = __builtin_bit_cast(unsigned, __builtin_amdgcn_cvt_pkrtz(s0, s1));
    unsigned b0 = __builtin_bit_cast(unsigned, __builtin_amdgcn_cvt_pkrtz(s4, s5));
    unsigned a1 = __builtin_bit_cast(unsigned, __builtin_amdgcn_cvt_pkrtz(s2, s3));
    unsigned b1 = __builtin_bit_cast(unsigned, __builtin_amdgcn_cvt_pkrtz(s6, s7));
    asm("v_permlane32_swap_b32 %0, %1" : "+v"(a0), "+v"(b0));
    asm("v_permlane32_swap_b32 %0, %1" : "+v"(a1), "+v"(b1));
    uint4v w = {a0, a1, b0, b1};
    return __builtin_bit_cast(half8, w);
}

__device__ inline half8 pack_noswap(float s0, float s1, float s2, float s3,
                                    float s4, float s5, float s6, float s7) {
    unsigned w0 = __builtin_bit_cast(unsigned, __builtin_amdgcn_cvt_pkrtz(s0, s1));
    unsigned w1 = __builtin_bit_cast(unsigned, __builtin_amdgcn_cvt_pkrtz(s2, s3));
    unsigned w2 = __builtin_bit_cast(unsigned, __builtin_amdgcn_cvt_pkrtz(s4, s5));
    unsigned w3 = __builtin_bit_cast(unsigned, __builtin_amdgcn_cvt_pkrtz(s6, s7));
    uint4v w = {w0, w1, w2, w3};
    return __builtin_bit_cast(half8, w);
}

__launch_bounds__(256)
__global__ void attn_kernel(const f16* __restrict__ Q, const f16* __restrict__ K,
                            const f16* __restrict__ Vt, const float* __restrict__ mask,
                            float* __restrict__ out) {
    __shared__ f16 Kt[64 * 72];
    __shared__ f16 Vtt[64 * 72];
    __shared__ float maskLds[2048];

    const float LOG2E = 1.4426950408889634f;
    int tid = threadIdx.x;
    int wid = tid >> 6, lane = tid & 63;
    int l31 = lane & 31, l5 = lane >> 5;
    int bh = blockIdx.y, b = bh >> 4, h = bh & 15;
    int q = blockIdx.x * 128 + wid * 32 + l31;

    // ---- runtime probe of the 32x32x16 B-operand k-layout ----
    // A = identity rows 0..15 in the (m214-verified) flat A layout; B slot (l5,j) = 8*l5+j.
    // D[row 4] == 4 -> B flat (k = 8*l5+j); == 8 -> two-block (k = 4*l5+(j&3)+8*(j>>2)).
    half8 pa, pcode;
    #pragma unroll
    for (int j = 0; j < 8; j++) { pa[j] = (f16)0; pcode[j] = (f16)(8 * l5 + j); }
    if (l31 < 16 && (l31 >> 3) == l5) pa[l31 & 7] = (f16)1;
    floatx16 pd = __builtin_amdgcn_mfma_f32_32x32x16_f16(pa, pcode, (floatx16)0.f, 0, 0, 0);
    float r4 = __shfl(pd[0], 32);     // D[row=4][col=0]
    bool twoblk = (r4 > 6.0f);

    // stage mask * log2e
    const float* maskp = mask + b * 2048;
    for (int i = tid; i < 512; i += 256) {
        float4 mv = ((const float4*)maskp)[i];
        mv.x *= LOG2E; mv.y *= LOG2E; mv.z *= LOG2E; mv.w *= LOG2E;
        ((float4*)maskLds)[i] = mv;
    }

    // Q frags pre-scaled by 0.125*log2e, laid out per the probed B k-map
    const f16* qrow = Q + ((size_t)bh * 1024 + q) * 64;
    half8 qf[4];
    if (!twoblk) {
        #pragma unroll
        for (int ks = 0; ks < 4; ks++)
            qf[ks] = *(const half8*)(qrow + ks * 16 + l5 * 8);
    } else {
        #pragma unroll
        for (int ks = 0; ks < 4; ks++) {
            half4 lo = *(const half4*)(qrow + ks * 16 + 4 * l5);
            half4 hi = *(const half4*)(qrow + ks * 16 + 8 + 4 * l5);
            qf[ks][0] = lo[0]; qf[ks][1] = lo[1]; qf[ks][2] = lo[2]; qf[ks][3] = lo[3];
            qf[ks][4] = hi[0]; qf[ks][5] = hi[1]; qf[ks][6] = hi[2]; qf[ks][7] = hi[3];
        }
    }
    const f16 qs = (f16)(0.125f * 1.4426950408889634f);
    #pragma unroll
    for (int ks = 0; ks < 4; ks++)
        #pragma unroll
        for (int x = 0; x < 8; x++) qf[ks][x] *= qs;

    floatx16 o0 = (floatx16)0.f, o1 = (floatx16)0.f;
    float m_run = -1e30f, l_run = 0.f;

    int sr = tid >> 2, sc = (tid & 3) * 16;
    const f16* Ksrc = K + ((size_t)bh * 2048 + sr) * 64 + sc;
    const f16* Vsrc = Vt + ((size_t)(bh * 64 + sr)) * 2048 + sc;

    for (int kv0 = 0; kv0 < 2048; kv0 += 64) {
        __syncthreads();
        *(half8*)&Kt[sr * 72 + sc]      = *(const half8*)(Ksrc + (size_t)kv0 * 64);
        *(half8*)&Kt[sr * 72 + sc + 8]  = *(const half8*)(Ksrc + (size_t)kv0 * 64 + 8);
        *(half8*)&Vtt[sr * 72 + sc]     = *(const half8*)(Vsrc + kv0);
        *(half8*)&Vtt[sr * 72 + sc + 8] = *(const half8*)(Vsrc + kv0 + 8);
        __syncthreads();

        // QK^T (swapped): A = K rows (flat layout), B = Q (probed layout)
        floatx16 sf0 = (floatx16)0.f, sf1 = (floatx16)0.f;
        #pragma unroll
        for (int ks = 0; ks < 4; ks++) {
            half8 k0 = *(const half8*)&Kt[l31 * 72 + ks * 16 + l5 * 8];
            half8 k1 = *(const half8*)&Kt[(32 + l31) * 72 + ks * 16 + l5 * 8];
            sf0 = __builtin_amdgcn_mfma_f32_32x32x16_f16(k0, qf[ks], sf0, 0, 0, 0);
            sf1 = __builtin_amdgcn_mfma_f32_32x32x16_f16(k1, qf[ks], sf1, 0, 0, 0);
        }

        // + mask (log2 domain), local max.  sf0[r]: kv = kv0 + (r&3)+8*(r>>2)+4*l5
        float pmax = -1e30f;
        #pragma unroll
        for (int g = 0; g < 4; g++) {
            float4 mk0 = *(const float4*)&maskLds[kv0 + 8 * g + 4 * l5];
            float4 mk1 = *(const float4*)&maskLds[kv0 + 32 + 8 * g + 4 * l5];
            #pragma unroll
            for (int i = 0; i < 4; i++) {
                sf0[4 * g + i] += ((const float*)&mk0)[i];
                sf1[4 * g + i] += ((const float*)&mk1)[i];
                pmax = fmaxf(pmax, fmaxf(sf0[4 * g + i], sf1[4 * g + i]));
            }
        }

        // defer-max rescale (THR=8 in log2 units)
        if (!__all(pmax - m_run <= 8.0f)) {
            float rmax = fmaxf(pmax, __shfl_xor(pmax, 32));
            float mnew = fmaxf(m_run, rmax);
            float alpha = exp2f(m_run - mnew);
            l_run *= alpha;
            #pragma unroll
            for (int r = 0; r < 16; r++) { o0[r] *= alpha; o1[r] *= alpha; }
            m_run = mnew;
        }

        // exp2 + sum
        float ls = 0.f;
        #pragma unroll
        for (int r = 0; r < 16; r++) {
            float p0 = exp2f(sf0[r] - m_run);
            float p1 = exp2f(sf1[r] - m_run);
            sf0[r] = p0; sf1[r] = p1;
            ls += p0 + p1;
        }
        ls += __shfl_xor(ls, 32);
        l_run += ls;

        // pack P into PV B-frags per probed layout
        half8 pb[4];
        if (!twoblk) {
            pb[0] = pack_swap(sf0[0], sf0[1], sf0[2], sf0[3], sf0[4], sf0[5], sf0[6], sf0[7]);
            pb[1] = pack_swap(sf0[8], sf0[9], sf0[10], sf0[11], sf0[12], sf0[13], sf0[14], sf0[15]);
            pb[2] = pack_swap(sf1[0], sf1[1], sf1[2], sf1[3], sf1[4], sf1[5], sf1[6], sf1[7]);
            pb[3] = pack_swap(sf1[8], sf1[9], sf1[10], sf1[11], sf1[12], sf1[13], sf1[14], sf1[15]);
        } else {
            pb[0] = pack_noswap(sf0[0], sf0[1], sf0[2], sf0[3], sf0[4], sf0[5], sf0[6], sf0[7]);
            pb[1] = pack_noswap(sf0[8], sf0[9], sf0[10], sf0[11], sf0[12], sf0[13], sf0[14], sf0[15]);
            pb[2] = pack_noswap(sf1[0], sf1[1], sf1[2], sf1[3], sf1[4], sf1[5], sf1[6], sf1[7]);
            pb[3] = pack_noswap(sf1[8], sf1[9], sf1[10], sf1[11], sf1[12], sf1[13], sf1[14], sf1[15]);
        }

        // PV (swapped): O^T[d][q] += V^T[d][kv] P^T[kv][q];  V as A (flat), P as B
        #pragma unroll
        for (int kb = 0; kb < 4; kb++) {
            half8 v0 = *(const half8*)&Vtt[l31 * 72 + kb * 16 + l5 * 8];
            half8 v1 = *(const half8*)&Vtt[(32 + l31) * 72 + kb * 16 + l5 * 8];
            o0 = __builtin_amdgcn_mfma_f32_32x32x16_f16(v0, pb[kb], o0, 0, 0, 0);
            o1 = __builtin_amdgcn_mfma_f32_32x32x16_f16(v1, pb[kb], o1, 0, 0, 0);
        }
    }

    // epilogue: o[dt][r] is O^T[d = dt*32 + (r&3)+8*(r>>2)+4*l5][q = l31]
    float inv = 1.f / l_run;
    float* orow = out + ((size_t)(b * 1024 + q)) * 1024 + h * 64;
    #pragma unroll
    for (int g = 0; g < 4; g++) {
        float4 r0 = {o0[4 * g] * inv, o0[4 * g + 1] * inv, o0[4 * g + 2] * inv, o0[4 * g + 3] * inv};
        float4 r1 = {o1[4 * g] * inv, o1[4 * g + 1] * inv, o1[4 * g + 2] * inv, o1[4 * g + 3] * inv};
        *(float4*)&orow[8 * g + 4 * l5]      = r0;
        *(float4*)&orow[32 + 8 * g + 4 * l5] = r1;
    }
}

// ---------------------------------------------------------------- launcher
extern "C" void kernel_launch(void* const* d_in, const int* in_sizes, int n_in,
                              void* d_out, int out_size, void* d_ws, size_t ws_size,
                              hipStream_t stream) {
    const float* hid  = (const float*)d_in[0];
    const float* enc  = (const float*)d_in[1];
    const float* mask = (const float*)d_in[2];
    const float* Wq   = (const float*)d_in[3];
    const float* bq   = (const float*)d_in[4];
    const float* Wk   = (const float*)d_in[5];
    const float* bk   = (const float*)d_in[6];
    const float* Wv   = (const float*)d_in[7];
    const float* bv   = (const float*)d_in[8];
    float* out = (float*)d_out;

    char* ws = (char*)d_ws;
    f16* Wtq = (f16*)(ws + (size_t)0);
    f16* Wtk = (f16*)(ws + ((size_t)2 << 20));
    f16* Wtv = (f16*)(ws + ((size_t)4 << 20));
    f16* Qw  = (f16*)(ws + ((size_t)6 << 20));
    f16* Kw  = (f16*)(ws + ((size_t)14 << 20));
    f16* Vw  = (f16*)(ws + ((size_t)30 << 20));
    f16* Vtw = (f16*)(ws + ((size_t)46 << 20));   // total 62 MiB

    dim3 tb(32, 8);
    wt_kernel<<<dim3(32, 32), tb, 0, stream>>>(Wq, Wtq);
    wt_kernel<<<dim3(32, 32), tb, 0, stream>>>(Wk, Wtk);
    wt_kernel<<<dim3(32, 32), tb, 0, stream>>>(Wv, Wtv);

    qkv_gemm<<<dim3(32, 8), 256, 0, stream>>>(hid, enc, Wtq, bq, Qw, 0);
    qkv_gemm<<<dim3(64, 8), 256, 0, stream>>>(hid, enc, Wtk, bk, Kw, 1);
    qkv_gemm<<<dim3(64, 8), 256, 0, stream>>>(hid, enc, Wtv, bv, Vw, 2);

    vt_kernel<<<dim3(2, 64, 64), tb, 0, stream>>>(Vw, Vtw);

    attn_kernel<<<dim3(8, 64), 256, 0, stream>>>(Qw, Kw, Vtw, mask, out);
}

// Round 6
// 168.878 us; speedup vs baseline: 1.4395x; 1.1691x over previous
//
#include <hip/hip_runtime.h>

// IncrementalRobertaSelfAttentionCross: B=4, Sq=1024, Skv=2048 (enc||dec), D=1024, H=16, HD=64
// Pipeline: Wt cast/transpose + A cast -> QKV GEMM (f16 MFMA, V writes V^T directly)
//           -> flash attn (32x32x16 swapped-QK^T, in-register softmax, 2-phase prefetch).

typedef _Float16 f16;
typedef __attribute__((ext_vector_type(4))) _Float16 half4;
typedef __attribute__((ext_vector_type(8))) _Float16 half8;
typedef __attribute__((ext_vector_type(4))) float floatx4;
typedef __attribute__((ext_vector_type(16))) float floatx16;
typedef __attribute__((ext_vector_type(4))) unsigned int uint4v;

// ---------------------------------------------------------------- W transpose
// W [1024 k][1024 n] f32  ->  Wt [1024 n][1024 k] f16
__global__ void wt_kernel(const float* __restrict__ W, f16* __restrict__ Wt) {
    __shared__ float tile[32][33];
    int k0 = blockIdx.y * 32, n0 = blockIdx.x * 32;
    int tx = threadIdx.x, ty = threadIdx.y;   // block (32,8)
    #pragma unroll
    for (int i = 0; i < 32; i += 8)
        tile[ty + i][tx] = W[(k0 + ty + i) * 1024 + n0 + tx];
    __syncthreads();
    #pragma unroll
    for (int i = 0; i < 32; i += 8)
        Wt[(n0 + ty + i) * 1024 + k0 + tx] = (f16)tile[tx][ty + i];
}

// ---------------------------------------------------------------- A cast
// Aall [b][r 0..2047][k], r<1024 = enc, r>=1024 = hid (f32 -> f16)
__global__ void cvt_kernel(const float* __restrict__ hid, const float* __restrict__ enc,
                           f16* __restrict__ Aall) {
    int t = blockIdx.x * 256 + threadIdx.x;   // 8192 rows * 128 thr/row
    int rowg = t >> 7, col = (t & 127) * 8;
    int b = rowg >> 11, r = rowg & 2047;
    const float* src = (r < 1024 ? enc + ((size_t)b * 1024 + r) * 1024
                                 : hid + ((size_t)b * 1024 + (r - 1024)) * 1024) + col;
    float4 v0 = *(const float4*)src, v1 = *(const float4*)(src + 4);
    half8 o;
    o[0] = (f16)v0.x; o[1] = (f16)v0.y; o[2] = (f16)v0.z; o[3] = (f16)v0.w;
    o[4] = (f16)v1.x; o[5] = (f16)v1.y; o[6] = (f16)v1.z; o[7] = (f16)v1.w;
    *(half8*)(Aall + (size_t)rowg * 1024 + col) = o;
}

// ---------------------------------------------------------------- QKV GEMM (f16 A)
// mode 0: Q (M=4096, Aall rows b*2048+1024+s) -> out [bh][s][64]
// mode 1: K (M=8192, Aall rows flat)          -> out [bh][s][64]
// mode 2: V (M=8192)                          -> out [bh][d][s]  (V^T, fused transpose)
__launch_bounds__(256)
__global__ void qkv_gemm(const f16* __restrict__ Aall, const f16* __restrict__ Wt,
                         const float* __restrict__ bias, f16* __restrict__ out, int mode) {
    __shared__ f16 At[128 * 40];
    __shared__ f16 Bt[128 * 40];

    int tid = threadIdx.x;
    int m0 = blockIdx.x * 128, n0 = blockIdx.y * 128;
    int wid = tid >> 6, lane = tid & 63;
    int wm = (wid >> 1) * 64, wn = (wid & 1) * 64;
    int lr = lane & 15, lg = lane >> 4;

    floatx4 acc[4][4];
    #pragma unroll
    for (int i = 0; i < 4; i++)
        #pragma unroll
        for (int j = 0; j < 4; j++) acc[i][j] = (floatx4)(0.f);

    int tr2 = tid >> 2, tk2 = (tid & 3) * 8;
    const f16 *a0src, *a1src;
    {
        int mA0 = m0 + tr2, mA1 = mA0 + 64;
        if (mode == 0) {
            int b0 = mA0 >> 10, b1 = mA1 >> 10;
            a0src = Aall + ((size_t)(b0 * 2048 + 1024 + (mA0 & 1023))) * 1024 + tk2;
            a1src = Aall + ((size_t)(b1 * 2048 + 1024 + (mA1 & 1023))) * 1024 + tk2;
        } else {
            a0src = Aall + (size_t)mA0 * 1024 + tk2;
            a1src = Aall + (size_t)mA1 * 1024 + tk2;
        }
    }
    const f16* b0src = Wt + (size_t)(n0 + tr2) * 1024 + tk2;
    const f16* b1src = Wt + (size_t)(n0 + tr2 + 64) * 1024 + tk2;

    half8 ra0 = *(const half8*)a0src, ra1 = *(const half8*)a1src;
    half8 rb0 = *(const half8*)b0src, rb1 = *(const half8*)b1src;

    for (int k0 = 0; k0 < 1024; k0 += 32) {
        __syncthreads();   // previous tile consumed
        *(half8*)&At[tr2 * 40 + tk2]        = ra0;
        *(half8*)&At[(tr2 + 64) * 40 + tk2] = ra1;
        *(half8*)&Bt[tr2 * 40 + tk2]        = rb0;
        *(half8*)&Bt[(tr2 + 64) * 40 + tk2] = rb1;
        __syncthreads();
        if (k0 < 992) {   // prefetch next K-step (in flight during MFMA)
            ra0 = *(const half8*)(a0src + k0 + 32);
            ra1 = *(const half8*)(a1src + k0 + 32);
            rb0 = *(const half8*)(b0src + k0 + 32);
            rb1 = *(const half8*)(b1src + k0 + 32);
        }

        half8 a[4], bf[4];
        #pragma unroll
        for (int i = 0; i < 4; i++)
            a[i] = *(const half8*)&At[(wm + i * 16 + lr) * 40 + lg * 8];
        #pragma unroll
        for (int j = 0; j < 4; j++)
            bf[j] = *(const half8*)&Bt[(wn + j * 16 + lr) * 40 + lg * 8];
        __builtin_amdgcn_s_setprio(1);
        #pragma unroll
        for (int i = 0; i < 4; i++)
            #pragma unroll
            for (int j = 0; j < 4; j++)
                acc[i][j] = __builtin_amdgcn_mfma_f32_16x16x32_f16(a[i], bf[j], acc[i][j], 0, 0, 0);
        __builtin_amdgcn_s_setprio(0);
    }

    if (mode == 2) {
        // V^T epilogue: contiguous half4 along s
        #pragma unroll
        for (int i = 0; i < 4; i++) {
            int mbase = m0 + wm + i * 16 + lg * 4;
            int b = mbase >> 11, s = mbase & 2047;
            #pragma unroll
            for (int j = 0; j < 4; j++) {
                int n = n0 + wn + j * 16 + lr;
                int h = n >> 6, d = n & 63;
                float bv = bias[n];
                half4 w;
                #pragma unroll
                for (int r = 0; r < 4; r++) w[r] = (f16)(acc[i][j][r] + bv);
                *(half4*)(out + ((size_t)((b * 16 + h) * 64 + d)) * 2048 + s) = w;
            }
        }
    } else {
        int Sout = (mode == 0) ? 1024 : 2048;
        #pragma unroll
        for (int i = 0; i < 4; i++) {
            int mbase = m0 + wm + i * 16 + lg * 4;
            #pragma unroll
            for (int j = 0; j < 4; j++) {
                int n = n0 + wn + j * 16 + lr;
                int h = n >> 6, d = n & 63;
                float bv = bias[n];
                #pragma unroll
                for (int r = 0; r < 4; r++) {
                    int m = mbase + r;
                    int b = (mode == 0) ? (m >> 10) : (m >> 11);
                    int s = (mode == 0) ? (m & 1023) : (m & 2047);
                    out[((size_t)(b * 16 + h) * Sout + s) * 64 + d] = (f16)(acc[i][j][r] + bv);
                }
            }
        }
    }
}

// ---------------------------------------------------------------- flash attention
__device__ inline half8 pack_swap(float s0, float s1, float s2, float s3,
                                  float s4, float s5, float s6, float s7) {
    unsigned a0 = __builtin_bit_cast(unsigned, __builtin_amdgcn_cvt_pkrtz(s0, s1));
    unsigned b0 = __builtin_bit_cast(unsigned, __builtin_amdgcn_cvt_pkrtz(s4, s5));
    unsigned a1 = __builtin_bit_cast(unsigned, __builtin_amdgcn_cvt_pkrtz(s2, s3));
    unsigned b1 = __builtin_bit_cast(unsigned, __builtin_amdgcn_cvt_pkrtz(s6, s7));
    asm("v_permlane32_swap_b32 %0, %1" : "+v"(a0), "+v"(b0));
    asm("v_permlane32_swap_b32 %0, %1" : "+v"(a1), "+v"(b1));
    uint4v w = {a0, a1, b0, b1};
    return __builtin_bit_cast(half8, w);
}

__device__ inline half8 pack_noswap(float s0, float s1, float s2, float s3,
                                    float s4, float s5, float s6, float s7) {
    unsigned w0 = __builtin_bit_cast(unsigned, __builtin_amdgcn_cvt_pkrtz(s0, s1));
    unsigned w1 = __builtin_bit_cast(unsigned, __builtin_amdgcn_cvt_pkrtz(s2, s3));
    unsigned w2 = __builtin_bit_cast(unsigned, __builtin_amdgcn_cvt_pkrtz(s4, s5));
    unsigned w3 = __builtin_bit_cast(unsigned, __builtin_amdgcn_cvt_pkrtz(s6, s7));
    uint4v w = {w0, w1, w2, w3};
    return __builtin_bit_cast(half8, w);
}

__launch_bounds__(256)
__global__ void attn_kernel(const f16* __restrict__ Q, const f16* __restrict__ K,
                            const f16* __restrict__ Vt, const float* __restrict__ mask,
                            float* __restrict__ out) {
    __shared__ f16 Kt[64 * 72];
    __shared__ f16 Vtt[64 * 72];
    __shared__ float maskLds[2048];

    const float LOG2E = 1.4426950408889634f;
    int tid = threadIdx.x;
    int wid = tid >> 6, lane = tid & 63;
    int l31 = lane & 31, l5 = lane >> 5;
    int bh = blockIdx.y, b = bh >> 4, h = bh & 15;
    int q = blockIdx.x * 128 + wid * 32 + l31;

    // runtime probe of the 32x32x16 B-operand k-layout (flat vs two-block)
    half8 pa, pcode;
    #pragma unroll
    for (int j = 0; j < 8; j++) { pa[j] = (f16)0; pcode[j] = (f16)(8 * l5 + j); }
    if (l31 < 16 && (l31 >> 3) == l5) pa[l31 & 7] = (f16)1;
    floatx16 pd = __builtin_amdgcn_mfma_f32_32x32x16_f16(pa, pcode, (floatx16)0.f, 0, 0, 0);
    float r4 = __shfl(pd[0], 32);
    bool twoblk = (r4 > 6.0f);

    // stage mask * log2e
    const float* maskp = mask + b * 2048;
    for (int i = tid; i < 512; i += 256) {
        float4 mv = ((const float4*)maskp)[i];
        mv.x *= LOG2E; mv.y *= LOG2E; mv.z *= LOG2E; mv.w *= LOG2E;
        ((float4*)maskLds)[i] = mv;
    }

    // Q frags pre-scaled by 0.125*log2e, laid out per the probed B k-map
    const f16* qrow = Q + ((size_t)bh * 1024 + q) * 64;
    half8 qf[4];
    if (!twoblk) {
        #pragma unroll
        for (int ks = 0; ks < 4; ks++)
            qf[ks] = *(const half8*)(qrow + ks * 16 + l5 * 8);
    } else {
        #pragma unroll
        for (int ks = 0; ks < 4; ks++) {
            half4 lo = *(const half4*)(qrow + ks * 16 + 4 * l5);
            half4 hi = *(const half4*)(qrow + ks * 16 + 8 + 4 * l5);
            qf[ks][0] = lo[0]; qf[ks][1] = lo[1]; qf[ks][2] = lo[2]; qf[ks][3] = lo[3];
            qf[ks][4] = hi[0]; qf[ks][5] = hi[1]; qf[ks][6] = hi[2]; qf[ks][7] = hi[3];
        }
    }
    const f16 qs = (f16)(0.125f * 1.4426950408889634f);
    #pragma unroll
    for (int ks = 0; ks < 4; ks++)
        #pragma unroll
        for (int x = 0; x < 8; x++) qf[ks][x] *= qs;

    floatx16 o0 = (floatx16)0.f, o1 = (floatx16)0.f;
    float m_run = -1e30f, l_run = 0.f;

    int sr = tid >> 2, sc = (tid & 3) * 16;
    const f16* Ksrc = K + ((size_t)bh * 2048 + sr) * 64 + sc;
    const f16* Vsrc = Vt + ((size_t)(bh * 64 + sr)) * 2048 + sc;

    // prologue prefetch of tile 0
    half8 rk0 = *(const half8*)(Ksrc);
    half8 rk1 = *(const half8*)(Ksrc + 8);
    half8 rv0 = *(const half8*)(Vsrc);
    half8 rv1 = *(const half8*)(Vsrc + 8);

    for (int kv0 = 0; kv0 < 2048; kv0 += 64) {
        __syncthreads();   // previous tile fully consumed (also covers mask staging, iter 0)
        *(half8*)&Kt[sr * 72 + sc]      = rk0;
        *(half8*)&Kt[sr * 72 + sc + 8]  = rk1;
        *(half8*)&Vtt[sr * 72 + sc]     = rv0;
        *(half8*)&Vtt[sr * 72 + sc + 8] = rv1;
        __syncthreads();
        if (kv0 < 2048 - 64) {   // prefetch next tile; latency hides under compute
            rk0 = *(const half8*)(Ksrc + (size_t)(kv0 + 64) * 64);
            rk1 = *(const half8*)(Ksrc + (size_t)(kv0 + 64) * 64 + 8);
            rv0 = *(const half8*)(Vsrc + kv0 + 64);
            rv1 = *(const half8*)(Vsrc + kv0 + 64 + 8);
        }

        // init S with mask (log2 domain): sf[r] -> kv = kv0 + (r&3)+8*(r>>2)+4*l5 (+32 for sf1)
        floatx16 sf0, sf1;
        #pragma unroll
        for (int g = 0; g < 4; g++) {
            float4 mk0 = *(const float4*)&maskLds[kv0 + 8 * g + 4 * l5];
            float4 mk1 = *(const float4*)&maskLds[kv0 + 32 + 8 * g + 4 * l5];
            #pragma unroll
            for (int i = 0; i < 4; i++) {
                sf0[4 * g + i] = ((const float*)&mk0)[i];
                sf1[4 * g + i] = ((const float*)&mk1)[i];
            }
        }

        // QK^T (swapped): A = K rows (flat layout), B = Q (probed layout)
        __builtin_amdgcn_s_setprio(1);
        #pragma unroll
        for (int ks = 0; ks < 4; ks++) {
            half8 k0 = *(const half8*)&Kt[l31 * 72 + ks * 16 + l5 * 8];
            half8 k1 = *(const half8*)&Kt[(32 + l31) * 72 + ks * 16 + l5 * 8];
            sf0 = __builtin_amdgcn_mfma_f32_32x32x16_f16(k0, qf[ks], sf0, 0, 0, 0);
            sf1 = __builtin_amdgcn_mfma_f32_32x32x16_f16(k1, qf[ks], sf1, 0, 0, 0);
        }
        __builtin_amdgcn_s_setprio(0);

        // local max (max3-shaped)
        float pmax = -1e30f;
        #pragma unroll
        for (int r = 0; r < 16; r++)
            pmax = fmaxf(pmax, fmaxf(sf0[r], sf1[r]));

        // defer-max rescale (THR=8 in log2 units)
        if (!__all(pmax - m_run <= 8.0f)) {
            float rmax = fmaxf(pmax, __shfl_xor(pmax, 32));
            float mnew = fmaxf(m_run, rmax);
            float alpha = exp2f(m_run - mnew);
            l_run *= alpha;
            #pragma unroll
            for (int r = 0; r < 16; r++) { o0[r] *= alpha; o1[r] *= alpha; }
            m_run = mnew;
        }

        // exp2 + sum
        float ls = 0.f;
        #pragma unroll
        for (int r = 0; r < 16; r++) {
            float p0 = exp2f(sf0[r] - m_run);
            float p1 = exp2f(sf1[r] - m_run);
            sf0[r] = p0; sf1[r] = p1;
            ls += p0 + p1;
        }
        ls += __shfl_xor(ls, 32);
        l_run += ls;

        // pack P into PV B-frags per probed layout
        half8 pb[4];
        if (!twoblk) {
            pb[0] = pack_swap(sf0[0], sf0[1], sf0[2], sf0[3], sf0[4], sf0[5], sf0[6], sf0[7]);
            pb[1] = pack_swap(sf0[8], sf0[9], sf0[10], sf0[11], sf0[12], sf0[13], sf0[14], sf0[15]);
            pb[2] = pack_swap(sf1[0], sf1[1], sf1[2], sf1[3], sf1[4], sf1[5], sf1[6], sf1[7]);
            pb[3] = pack_swap(sf1[8], sf1[9], sf1[10], sf1[11], sf1[12], sf1[13], sf1[14], sf1[15]);
        } else {
            pb[0] = pack_noswap(sf0[0], sf0[1], sf0[2], sf0[3], sf0[4], sf0[5], sf0[6], sf0[7]);
            pb[1] = pack_noswap(sf0[8], sf0[9], sf0[10], sf0[11], sf0[12], sf0[13], sf0[14], sf0[15]);
            pb[2] = pack_noswap(sf1[0], sf1[1], sf1[2], sf1[3], sf1[4], sf1[5], sf1[6], sf1[7]);
            pb[3] = pack_noswap(sf1[8], sf1[9], sf1[10], sf1[11], sf1[12], sf1[13], sf1[14], sf1[15]);
        }

        // PV (swapped): O^T[d][q] += V^T[d][kv] P^T[kv][q]
        __builtin_amdgcn_s_setprio(1);
        #pragma unroll
        for (int kb = 0; kb < 4; kb++) {
            half8 v0 = *(const half8*)&Vtt[l31 * 72 + kb * 16 + l5 * 8];
            half8 v1 = *(const half8*)&Vtt[(32 + l31) * 72 + kb * 16 + l5 * 8];
            o0 = __builtin_amdgcn_mfma_f32_32x32x16_f16(v0, pb[kb], o0, 0, 0, 0);
            o1 = __builtin_amdgcn_mfma_f32_32x32x16_f16(v1, pb[kb], o1, 0, 0, 0);
        }
        __builtin_amdgcn_s_setprio(0);
    }

    // epilogue: o[dt][r] is O^T[d = dt*32 + (r&3)+8*(r>>2)+4*l5][q = l31]
    float inv = 1.f / l_run;
    float* orow = out + ((size_t)(b * 1024 + q)) * 1024 + h * 64;
    #pragma unroll
    for (int g = 0; g < 4; g++) {
        float4 r0 = {o0[4 * g] * inv, o0[4 * g + 1] * inv, o0[4 * g + 2] * inv, o0[4 * g + 3] * inv};
        float4 r1 = {o1[4 * g] * inv, o1[4 * g + 1] * inv, o1[4 * g + 2] * inv, o1[4 * g + 3] * inv};
        *(float4*)&orow[8 * g + 4 * l5]      = r0;
        *(float4*)&orow[32 + 8 * g + 4 * l5] = r1;
    }
}

// ---------------------------------------------------------------- launcher
extern "C" void kernel_launch(void* const* d_in, const int* in_sizes, int n_in,
                              void* d_out, int out_size, void* d_ws, size_t ws_size,
                              hipStream_t stream) {
    const float* hid  = (const float*)d_in[0];
    const float* enc  = (const float*)d_in[1];
    const float* mask = (const float*)d_in[2];
    const float* Wq   = (const float*)d_in[3];
    const float* bq   = (const float*)d_in[4];
    const float* Wk   = (const float*)d_in[5];
    const float* bk   = (const float*)d_in[6];
    const float* Wv   = (const float*)d_in[7];
    const float* bv   = (const float*)d_in[8];
    float* out = (float*)d_out;

    char* ws = (char*)d_ws;
    f16* Wtq  = (f16*)(ws + ((size_t)0 << 20));
    f16* Wtk  = (f16*)(ws + ((size_t)2 << 20));
    f16* Wtv  = (f16*)(ws + ((size_t)4 << 20));
    f16* Aall = (f16*)(ws + ((size_t)6 << 20));   // 16 MiB
    f16* Qw   = (f16*)(ws + ((size_t)22 << 20));  // 8 MiB
    f16* Kw   = (f16*)(ws + ((size_t)30 << 20));  // 16 MiB
    f16* Vtw  = (f16*)(ws + ((size_t)46 << 20));  // 16 MiB -> total 62 MiB

    dim3 tb(32, 8);
    wt_kernel<<<dim3(32, 32), tb, 0, stream>>>(Wq, Wtq);
    wt_kernel<<<dim3(32, 32), tb, 0, stream>>>(Wk, Wtk);
    wt_kernel<<<dim3(32, 32), tb, 0, stream>>>(Wv, Wtv);
    cvt_kernel<<<4096, 256, 0, stream>>>(hid, enc, Aall);

    qkv_gemm<<<dim3(32, 8), 256, 0, stream>>>(Aall, Wtq, bq, Qw, 0);
    qkv_gemm<<<dim3(64, 8), 256, 0, stream>>>(Aall, Wtk, bk, Kw, 1);
    qkv_gemm<<<dim3(64, 8), 256, 0, stream>>>(Aall, Wtv, bv, Vtw, 2);

    attn_kernel<<<dim3(8, 64), 256, 0, stream>>>(Qw, Kw, Vtw, mask, out);
}